// Round 1
// baseline (142.954 us; speedup 1.0000x reference)
//
#include <hip/hip_runtime.h>
#include <math.h>

#define DIM 256
#define HID 256
#define NB_MAIN 2048

// ---------------- Kernel A: Q[h] = sum_d W_query[h,d] * query[d] ----------------
// grid 64 blocks x 256 threads; one wave per h.
__global__ void qba_compute_Q(const float* __restrict__ Wq,
                              const float* __restrict__ query,
                              float* __restrict__ Q) {
  int lane = threadIdx.x & 63;
  int wid  = threadIdx.x >> 6;
  int h = blockIdx.x * 4 + wid;
  float4 w = reinterpret_cast<const float4*>(Wq + (size_t)h * DIM)[lane];
  float4 q = reinterpret_cast<const float4*>(query)[lane];
  float acc = w.x * q.x + w.y * q.y + w.z * q.z + w.w * q.w;
  #pragma unroll
  for (int off = 32; off > 0; off >>= 1) acc += __shfl_xor(acc, off);
  if (lane == 0) Q[h] = acc;
}

// ---------------- Kernel B: q_eff[d] = (1/16) * sum_h Wk[h,d]*Q[h];
//                            v_eff[d] = sum_h Wv[h,d]*Wout[h] ----------------
// grid 64 blocks x 256 threads; block b handles h in [4b,4b+4). q_eff/v_eff pre-zeroed.
__global__ void qba_compute_eff(const float* __restrict__ Wk,
                                const float* __restrict__ Wv,
                                const float* __restrict__ Q,
                                const float* __restrict__ Wout,
                                float* __restrict__ q_eff,
                                float* __restrict__ v_eff) {
  int d = threadIdx.x;
  int h0 = blockIdx.x * 4;
  float aq = 0.f, av = 0.f;
  #pragma unroll
  for (int i = 0; i < 4; ++i) {
    int h = h0 + i;
    aq += Wk[(size_t)h * DIM + d] * Q[h];
    av += Wv[(size_t)h * DIM + d] * Wout[h];
  }
  atomicAdd(&q_eff[d], aq * 0.0625f);   // fold 1/sqrt(256)
  atomicAdd(&v_eff[d], av);
}

// ---------------- Kernel C: main streaming pass ----------------
// one wave per row; lane loads float4 at d = lane*4. Computes s[n], t[n],
// per-block online softmax stats (m, l) over unmasked rows.
__global__ void __launch_bounds__(256)
qba_main(const float* __restrict__ inputs,
         const int* __restrict__ mask,
         const float* __restrict__ q_eff,
         const float* __restrict__ v_eff,
         float* __restrict__ s_buf,
         float* __restrict__ t_buf,
         float* __restrict__ block_m,
         float* __restrict__ block_l,
         int N) {
  int lane = threadIdx.x & 63;
  int wid  = threadIdx.x >> 6;
  int gw = blockIdx.x * 4 + wid;
  int nw = gridDim.x * 4;
  float4 qe = reinterpret_cast<const float4*>(q_eff)[lane];
  float4 ve = reinterpret_cast<const float4*>(v_eff)[lane];
  float m = -INFINITY, l = 0.f;
  for (int n = gw; n < N; n += nw) {
    float4 x = reinterpret_cast<const float4*>(inputs + (size_t)n * DIM)[lane];
    float s = x.x * qe.x + x.y * qe.y + x.z * qe.z + x.w * qe.w;
    float t = x.x * ve.x + x.y * ve.y + x.z * ve.z + x.w * ve.w;
    #pragma unroll
    for (int off = 32; off > 0; off >>= 1) {
      s += __shfl_xor(s, off);
      t += __shfl_xor(t, off);
    }
    int mk = mask[n];  // wave-uniform
    if (lane == 0) {
      s_buf[n] = mk ? s : -INFINITY;
      t_buf[n] = t;
    }
    if (mk) {  // all lanes update redundantly (no divergence within wave)
      float mn = fmaxf(m, s);
      l = l * expf(m - mn) + expf(s - mn);  // first iter: 0*exp(-inf)=0, ok
      m = mn;
    }
  }
  __shared__ float sm[4], sl[4];
  if (lane == 0) { sm[wid] = m; sl[wid] = l; }
  __syncthreads();
  if (threadIdx.x == 0) {
    float M = -INFINITY, L = 0.f;
    #pragma unroll
    for (int i = 0; i < 4; ++i) M = fmaxf(M, sm[i]);
    #pragma unroll
    for (int i = 0; i < 4; ++i) if (sl[i] != 0.f) L += sl[i] * expf(sm[i] - M);
    block_m[blockIdx.x] = M;
    block_l[blockIdx.x] = L;
  }
}

// ---------------- Kernel D: combine 2048 block stats -> global (M, 1/S) ----------------
__device__ inline void sm_combine(float& m, float& l, float bm, float bl) {
  float mn = fmaxf(m, bm);
  float e1 = (l  != 0.f) ? expf(m  - mn) : 0.f;  // guards -inf - -inf = NaN
  float e2 = (bl != 0.f) ? expf(bm - mn) : 0.f;
  l = l * e1 + bl * e2;
  m = mn;
}

__global__ void qba_combine(const float* __restrict__ block_m,
                            const float* __restrict__ block_l,
                            float* __restrict__ MS, int NB) {
  int tid = threadIdx.x;  // single block, 256 threads
  int lane = tid & 63, wid = tid >> 6;
  float m = -INFINITY, l = 0.f;
  for (int i = tid; i < NB; i += 256) {
    sm_combine(m, l, block_m[i], block_l[i]);
  }
  #pragma unroll
  for (int off = 32; off > 0; off >>= 1) {
    float bm = __shfl_xor(m, off);
    float bl = __shfl_xor(l, off);
    sm_combine(m, l, bm, bl);
  }
  __shared__ float sm[4], sl[4];
  if (lane == 0) { sm[wid] = m; sl[wid] = l; }
  __syncthreads();
  if (tid == 0) {
    float M = sm[0], L = sl[0];
    #pragma unroll
    for (int i = 1; i < 4; ++i) sm_combine(M, L, sm[i], sl[i]);
    MS[0] = M;
    MS[1] = 1.f / L;
  }
}

// ---------------- Kernel E: finalize ----------------
__global__ void qba_final(const float* __restrict__ s_buf,
                          const float* __restrict__ t_buf,
                          const float* __restrict__ MS,
                          float* __restrict__ out, int N) {
  int i = blockIdx.x * blockDim.x + threadIdx.x;
  if (i >= N) return;
  float M = MS[0], invS = MS[1];
  float w = expf(s_buf[i] - M) * invS;  // masked: exp(-inf)=0
  out[i] = 10.f * tanhf(w * t_buf[i]);
}

extern "C" void kernel_launch(void* const* d_in, const int* in_sizes, int n_in,
                              void* d_out, int out_size, void* d_ws, size_t ws_size,
                              hipStream_t stream) {
  const float* inputs = (const float*)d_in[0];
  const float* query  = (const float*)d_in[1];
  const int*   mask   = (const int*)d_in[2];
  const float* Wq     = (const float*)d_in[3];
  const float* Wk     = (const float*)d_in[4];
  const float* Wv     = (const float*)d_in[5];
  const float* Wout   = (const float*)d_in[6];
  float* out = (float*)d_out;
  int N = in_sizes[2];

  float* ws     = (float*)d_ws;
  float* s_buf  = ws;                 // N
  float* t_buf  = s_buf + N;          // N
  float* Qbuf   = t_buf + N;          // 256
  float* q_eff  = Qbuf + HID;         // 256
  float* v_eff  = q_eff + DIM;        // 256
  float* bm     = v_eff + DIM;        // NB_MAIN
  float* bl     = bm + NB_MAIN;       // NB_MAIN
  float* MS     = bl + NB_MAIN;       // 2

  hipMemsetAsync(q_eff, 0, 2 * DIM * sizeof(float), stream);
  qba_compute_Q  <<<HID / 4, 256, 0, stream>>>(Wq, query, Qbuf);
  qba_compute_eff<<<HID / 4, 256, 0, stream>>>(Wk, Wv, Qbuf, Wout, q_eff, v_eff);
  qba_main       <<<NB_MAIN, 256, 0, stream>>>(inputs, mask, q_eff, v_eff,
                                               s_buf, t_buf, bm, bl, N);
  qba_combine    <<<1, 256, 0, stream>>>(bm, bl, MS, NB_MAIN);
  qba_final      <<<(N + 255) / 256, 256, 0, stream>>>(s_buf, t_buf, MS, out, N);
}

// Round 2
// 102.875 us; speedup vs baseline: 1.3896x; 1.3896x over previous
//
#include <hip/hip_runtime.h>
#include <math.h>

typedef float f4 __attribute__((ext_vector_type(4)));

#define DIM 256
#define NF4 64          // float4 chunks per row
#define NB_MAIN 2048

__device__ inline float dot4(f4 a, f4 b) {
  return a.x * b.x + a.y * b.y + a.z * b.z + a.w * b.w;
}

__device__ inline void sm_combine(float& m, float& l, float bm, float bl) {
  float mn = fmaxf(m, bm);
  float e1 = (l  != 0.f) ? __expf(m  - mn) : 0.f;  // guards -inf - -inf = NaN
  float e2 = (bl != 0.f) ? __expf(bm - mn) : 0.f;
  l = l * e1 + bl * e2;
  m = mn;
}

// ---------------- Kernel A: Q[h] = sum_d Wq[h,d]*query[d]; 64 blocks, wave/h --
__global__ void qba_compute_Q(const float* __restrict__ Wq,
                              const float* __restrict__ query,
                              float* __restrict__ Q) {
  int lane = threadIdx.x & 63;
  int wid  = threadIdx.x >> 6;
  int h = blockIdx.x * 4 + wid;
  f4 w = reinterpret_cast<const f4*>(Wq + (size_t)h * DIM)[lane];
  f4 q = reinterpret_cast<const f4*>(query)[lane];
  float acc = dot4(w, q);
  #pragma unroll
  for (int off = 32; off > 0; off >>= 1) acc += __shfl_xor(acc, off);
  if (lane == 0) Q[h] = acc;
}

// ---------------- Kernel B: q_eff[d] = (1/16)*sum_h Wk[h,d]*Q[h]  (block 0)
//                            v_eff[d] = sum_h Wv[h,d]*Wout[h]      (block 1)
// coalesced column sums (thread d, contiguous across lanes), no atomics -------
__global__ void qba_compute_eff(const float* __restrict__ Wk,
                                const float* __restrict__ Wv,
                                const float* __restrict__ Q,
                                const float* __restrict__ Wout,
                                float* __restrict__ q_eff,
                                float* __restrict__ v_eff) {
  int d = threadIdx.x;
  if (blockIdx.x == 0) {
    float a = 0.f;
    #pragma unroll 8
    for (int h = 0; h < DIM; ++h) a += Wk[(size_t)h * DIM + d] * Q[h];
    q_eff[d] = a * 0.0625f;                       // fold 1/sqrt(256)
  } else {
    float a = 0.f;
    #pragma unroll 8
    for (int h = 0; h < DIM; ++h) a += Wv[(size_t)h * DIM + d] * Wout[h];
    v_eff[d] = a;
  }
}

// ---------------- Kernel C: main streaming pass ----------------
// 4 rows per wave: group g = lane>>4 owns row n0+g; lane reads 4 float4s at
// chunk sub+16k. Butterfly over 4 steps (within 16-lane group) reduces both
// dots; online (m,l) per lane, group-combined at loop end.
__global__ void __launch_bounds__(256)
qba_main(const float* __restrict__ inputs,
         const int* __restrict__ mask,
         const float* __restrict__ q_eff,
         const float* __restrict__ v_eff,
         float* __restrict__ s_buf,
         float* __restrict__ t_buf,
         float* __restrict__ block_m,
         float* __restrict__ block_l,
         int N) {
  int lane = threadIdx.x & 63;
  int wid  = threadIdx.x >> 6;
  int g    = lane >> 4;
  int sub  = lane & 15;
  const f4* in4 = reinterpret_cast<const f4*>(inputs);

  f4 qe[4], ve[4];
  #pragma unroll
  for (int k = 0; k < 4; ++k) {
    qe[k] = reinterpret_cast<const f4*>(q_eff)[sub + 16 * k];
    ve[k] = reinterpret_cast<const f4*>(v_eff)[sub + 16 * k];
  }

  int wave   = blockIdx.x * 4 + wid;
  int stride = NB_MAIN * 4 * 4;              // total rows per sweep
  float m = -INFINITY, l = 0.f;

  for (int n0 = wave * 4; n0 < N; n0 += stride) {
    int row  = n0 + g;
    int rowc = row < N ? row : N - 1;
    const f4* rp = in4 + (size_t)rowc * NF4 + sub;
    f4 x0 = __builtin_nontemporal_load(rp);
    f4 x1 = __builtin_nontemporal_load(rp + 16);
    f4 x2 = __builtin_nontemporal_load(rp + 32);
    f4 x3 = __builtin_nontemporal_load(rp + 48);
    int mk = mask[rowc];                      // group-uniform broadcast

    float s = dot4(x0, qe[0]) + dot4(x1, qe[1]) + dot4(x2, qe[2]) + dot4(x3, qe[3]);
    float t = dot4(x0, ve[0]) + dot4(x1, ve[1]) + dot4(x2, ve[2]) + dot4(x3, ve[3]);
    #pragma unroll
    for (int off = 1; off < 16; off <<= 1) {
      s += __shfl_xor(s, off);
      t += __shfl_xor(t, off);
    }

    if (row < N) {
      if (sub == 0) {
        s_buf[row] = mk ? s : -INFINITY;
        t_buf[row] = t;
      }
      if (mk) {                               // group-uniform predicate
        float mn = fmaxf(m, s);
        l = l * __expf(m - mn) + __expf(s - mn);
        m = mn;
      }
    }
  }

  // combine the 4 groups' stats across the wave
  #pragma unroll
  for (int off = 16; off < 64; off <<= 1) {
    float bm = __shfl_xor(m, off);
    float bl = __shfl_xor(l, off);
    sm_combine(m, l, bm, bl);
  }

  __shared__ float sm[4], sl[4];
  if (lane == 0) { sm[wid] = m; sl[wid] = l; }
  __syncthreads();
  if (threadIdx.x == 0) {
    float M = sm[0], L = sl[0];
    #pragma unroll
    for (int i = 1; i < 4; ++i) sm_combine(M, L, sm[i], sl[i]);
    block_m[blockIdx.x] = M;
    block_l[blockIdx.x] = L;
  }
}

// ---------------- Kernel D: combine 2048 block stats -> (M, 1/S) -------------
__global__ void qba_combine(const float* __restrict__ block_m,
                            const float* __restrict__ block_l,
                            float* __restrict__ MS, int NB) {
  int tid = threadIdx.x;  // single block, 256 threads
  int lane = tid & 63, wid = tid >> 6;
  float m = -INFINITY, l = 0.f;
  for (int i = tid; i < NB; i += 256) sm_combine(m, l, block_m[i], block_l[i]);
  #pragma unroll
  for (int off = 32; off > 0; off >>= 1) {
    float bm = __shfl_xor(m, off);
    float bl = __shfl_xor(l, off);
    sm_combine(m, l, bm, bl);
  }
  __shared__ float sm[4], sl[4];
  if (lane == 0) { sm[wid] = m; sl[wid] = l; }
  __syncthreads();
  if (tid == 0) {
    float M = sm[0], L = sl[0];
    #pragma unroll
    for (int i = 1; i < 4; ++i) sm_combine(M, L, sm[i], sl[i]);
    MS[0] = M;
    MS[1] = 1.f / L;
  }
}

// ---------------- Kernel E: finalize (vectorized, N % 4 == 0) ----------------
__global__ void qba_final(const f4* __restrict__ s4,
                          const f4* __restrict__ t4,
                          const float* __restrict__ MS,
                          f4* __restrict__ out4, int N4) {
  int i = blockIdx.x * blockDim.x + threadIdx.x;
  if (i >= N4) return;
  float M = MS[0], invS = MS[1];
  f4 s = s4[i], t = t4[i];
  f4 r;
  r.x = 10.f * tanhf(__expf(s.x - M) * invS * t.x);
  r.y = 10.f * tanhf(__expf(s.y - M) * invS * t.y);
  r.z = 10.f * tanhf(__expf(s.z - M) * invS * t.z);
  r.w = 10.f * tanhf(__expf(s.w - M) * invS * t.w);
  out4[i] = r;
}

extern "C" void kernel_launch(void* const* d_in, const int* in_sizes, int n_in,
                              void* d_out, int out_size, void* d_ws, size_t ws_size,
                              hipStream_t stream) {
  const float* inputs = (const float*)d_in[0];
  const float* query  = (const float*)d_in[1];
  const int*   mask   = (const int*)d_in[2];
  const float* Wq     = (const float*)d_in[3];
  const float* Wk     = (const float*)d_in[4];
  const float* Wv     = (const float*)d_in[5];
  const float* Wout   = (const float*)d_in[6];
  float* out = (float*)d_out;
  int N = in_sizes[2];

  float* ws     = (float*)d_ws;
  float* s_buf  = ws;                 // N
  float* t_buf  = s_buf + N;          // N
  float* Qbuf   = t_buf + N;          // 256
  float* q_eff  = Qbuf + DIM;         // 256
  float* v_eff  = q_eff + DIM;        // 256
  float* bm     = v_eff + DIM;        // NB_MAIN
  float* bl     = bm + NB_MAIN;       // NB_MAIN
  float* MS     = bl + NB_MAIN;       // 2

  qba_compute_Q  <<<DIM / 4, 256, 0, stream>>>(Wq, query, Qbuf);
  qba_compute_eff<<<2, 256, 0, stream>>>(Wk, Wv, Qbuf, Wout, q_eff, v_eff);
  qba_main       <<<NB_MAIN, 256, 0, stream>>>(inputs, mask, q_eff, v_eff,
                                               s_buf, t_buf, bm, bl, N);
  qba_combine    <<<1, 256, 0, stream>>>(bm, bl, MS, NB_MAIN);
  qba_final      <<<(N / 4 + 255) / 256, 256, 0, stream>>>(
      (const f4*)s_buf, (const f4*)t_buf, MS, (f4*)out, N / 4);
}